// Round 2
// baseline (611.766 us; speedup 1.0000x reference)
//
#include <hip/hip_runtime.h>

#define BB 64
#define SS 2048
#define DD 1024
#define SCHUNK 64
#define NC (SS / SCHUNK)   // 32 s-chunks

typedef float f32x4 __attribute__((ext_vector_type(4)));

// Pass 1: per (b, s-chunk) masked partial sum over D.
// vs round 1: SCHUNK 128->64 doubles the grid to 2048 blocks (8 blocks/CU,
// 32 waves/CU = full occupancy) to double the latency-hiding pool — pass 1
// was measured at ~3 TB/s, half the 6.3 TB/s this box's fills reach.
// Addressing via wave-uniform base + 32-bit voffset (SGPR-base form, fewer
// VALU ops, VGPRs fit 8 blocks/CU, enforced by __launch_bounds__(256,8)).
__global__ __launch_bounds__(256, 8) void ep_partial(
    const float* __restrict__ hidden, const int* __restrict__ mask,
    float* __restrict__ wsm, float* __restrict__ wscnt)
{
    const int b = blockIdx.x;
    const int c = blockIdx.y;
    const int t = threadIdx.x;

    __shared__ unsigned char sidx[SCHUNK];
    __shared__ int s_n;

    // wave 0 classifies the 64 mask entries of this chunk
    if (t < 64) {
        const int m = (mask[b * SS + c * SCHUNK + t] != 0) ? 1 : 0;
        const unsigned long long bal = __ballot(m);
        const int pre = __popcll(bal & ((1ull << t) - 1ull));
        if (m) sidx[pre] = (unsigned char)t;
        if (t == 0) s_n = __popcll(bal);
    }
    __syncthreads();
    const int n1 = s_n;

    // wave-uniform base (SGPR pair) + 32-bit per-lane byte offset
    const char* base = (const char*)hidden
                     + (size_t)(b * SS + c * SCHUNK) * DD * sizeof(float);
    const unsigned toff = (unsigned)t * 16u;

    f32x4 am = {0.f, 0.f, 0.f, 0.f};

    int i = 0;
    for (; i + 8 <= n1; i += 8) {
        const unsigned o0 = (unsigned)sidx[i + 0] * 4096u + toff;
        const unsigned o1 = (unsigned)sidx[i + 1] * 4096u + toff;
        const unsigned o2 = (unsigned)sidx[i + 2] * 4096u + toff;
        const unsigned o3 = (unsigned)sidx[i + 3] * 4096u + toff;
        const unsigned o4 = (unsigned)sidx[i + 4] * 4096u + toff;
        const unsigned o5 = (unsigned)sidx[i + 5] * 4096u + toff;
        const unsigned o6 = (unsigned)sidx[i + 6] * 4096u + toff;
        const unsigned o7 = (unsigned)sidx[i + 7] * 4096u + toff;
        f32x4 v0 = __builtin_nontemporal_load((const f32x4*)(base + o0));
        f32x4 v1 = __builtin_nontemporal_load((const f32x4*)(base + o1));
        f32x4 v2 = __builtin_nontemporal_load((const f32x4*)(base + o2));
        f32x4 v3 = __builtin_nontemporal_load((const f32x4*)(base + o3));
        f32x4 v4 = __builtin_nontemporal_load((const f32x4*)(base + o4));
        f32x4 v5 = __builtin_nontemporal_load((const f32x4*)(base + o5));
        f32x4 v6 = __builtin_nontemporal_load((const f32x4*)(base + o6));
        f32x4 v7 = __builtin_nontemporal_load((const f32x4*)(base + o7));
        // ascending s-order, single accumulator
        am += v0; am += v1; am += v2; am += v3;
        am += v4; am += v5; am += v6; am += v7;
    }
    for (; i < n1; ++i) {
        const unsigned o = (unsigned)sidx[i] * 4096u + toff;
        am += __builtin_nontemporal_load((const f32x4*)(base + o));
    }

    reinterpret_cast<f32x4*>(wsm)[(size_t)(b * NC + c) * (DD / 4) + t] = am;
    if (t == 0) wscnt[b * NC + c] = (float)n1;
}

// Pass 2: 256 blocks (b x quarter-of-D), one wave each. Sums the 32 chunk
// partials + chunk counts, divides. cnt==0 fallback (never taken on this
// data) recomputes the full mean directly from hidden.
__global__ __launch_bounds__(64) void ep_finalize(
    const float* __restrict__ wsm, const float* __restrict__ wscnt,
    const float* __restrict__ hidden, float* __restrict__ out)
{
    const int b    = blockIdx.x;
    const int q    = blockIdx.y;            // D quarter
    const int lane = threadIdx.x;           // 0..63
    const int d4   = q * 64 + lane;         // float4 column in [0,256)

    float cnt = 0.f;
    #pragma unroll
    for (int c = 0; c < NC; ++c) cnt += wscnt[b * NC + c];   // uniform -> s_loads

    const f32x4* pm = reinterpret_cast<const f32x4*>(wsm)
                      + (size_t)b * NC * (DD / 4) + d4;
    f32x4 am = {0.f, 0.f, 0.f, 0.f};
    #pragma unroll
    for (int c = 0; c < NC; ++c) am += pm[(size_t)c * (DD / 4)];

    f32x4 r;
    if (cnt > 0.f) {
        r.x = am.x / cnt; r.y = am.y / cnt; r.z = am.z / cnt; r.w = am.w / cnt;
    } else {
        // all-zero mask row: full mean (cold path, kept for correctness)
        const f32x4* hp = reinterpret_cast<const f32x4*>(hidden)
                          + (size_t)b * SS * (DD / 4) + d4;
        f32x4 af = {0.f, 0.f, 0.f, 0.f};
        for (int s = 0; s < SS; ++s) af += hp[(size_t)s * (DD / 4)];
        const float invS = 1.0f / (float)SS;
        r.x = af.x * invS; r.y = af.y * invS; r.z = af.z * invS; r.w = af.w * invS;
    }
    reinterpret_cast<f32x4*>(out)[(size_t)b * (DD / 4) + d4] = r;
}

extern "C" void kernel_launch(void* const* d_in, const int* in_sizes, int n_in,
                              void* d_out, int out_size, void* d_ws, size_t ws_size,
                              hipStream_t stream) {
    const float* hidden = (const float*)d_in[0];
    const int*   mask   = (const int*)d_in[1];
    float*       out    = (float*)d_out;

    // workspace: [B*NC*D] masked partials (8 MiB) | [B*NC] chunk counts
    float* wsm   = (float*)d_ws;
    float* wscnt = wsm + (size_t)BB * NC * DD;

    ep_partial<<<dim3(BB, NC), 256, 0, stream>>>(hidden, mask, wsm, wscnt);
    ep_finalize<<<dim3(BB, 4), 64, 0, stream>>>(wsm, wscnt, hidden, out);
}